// Round 4
// baseline (142.126 us; speedup 1.0000x reference)
//
#include <hip/hip_runtime.h>

// SparseFlowModel: per-batch voxel neighbor queries.
// coords: [4, 2048, 3] int32 in [0,64). Outputs (concat flat, float32):
//   prior [4,2048,4096] then occ [4,2048,26].
//
// Reference hash (x*100003 + y*1009 + z) is injective over [-1,64]^3 ->
// membership == exact coord-triple membership; out-of-range neighbors absent.
//
// Structure (3 stream-ordered nodes, all tiny except compute):
//   1. hipMemsetAsync: zero 128 KB bitmap in d_ws (ws is poisoned 0xAA).
//   2. scatter_bits: 8192 atomicOr into per-batch 64^3 bitmaps (~2 us).
//   3. compute: one block per point, no LDS (32 waves/CU resident),
//      wave-uniform scalar loads for coords + face bits, hoisted z-pattern,
//      nontemporal float4 stores. Floor = 134 MB writes ~= 21 us @ 6.3 TB/s.

#define B 4
#define N 2048
#define BM_WORDS 8192                        // 64^3 / 32 per batch
#define PRIOR_ELEMS (4ull * 2048ull * 4096ull)

typedef float vfloat4 __attribute__((ext_vector_type(4)));   // clang vector: ok for nontemporal builtin

static __device__ __constant__ int NB_OFF[26][3] = {
    {-1,0,0},{1,0,0},{0,-1,0},{0,1,0},{0,0,-1},{0,0,1},
    {-1,-1,0},{-1,1,0},{1,-1,0},{1,1,0},
    {-1,0,-1},{-1,0,1},{1,0,-1},{1,0,1},
    {0,-1,-1},{0,-1,1},{0,1,-1},{0,1,1},
    {-1,-1,-1},{-1,-1,1},{-1,1,-1},{-1,1,1},
    {1,-1,-1},{1,-1,1},{1,1,-1},{1,1,1}
};

__device__ __forceinline__ bool bm_test(const unsigned* __restrict__ bm,
                                        int x, int y, int z) {
    if (((x | y | z) & ~63) != 0) return false;   // negatives or >=64
    unsigned idx = ((unsigned)x << 12) | ((unsigned)y << 6) | (unsigned)z;
    return (bm[idx >> 5] >> (idx & 31u)) & 1u;
}

__global__ void scatter_bits(const int* __restrict__ coords,
                             unsigned* __restrict__ bm) {
    int id = blockIdx.x * blockDim.x + threadIdx.x;   // 0..8191
    if (id >= B * N) return;
    int b = id >> 11;
    int x = coords[id * 3 + 0];
    int y = coords[id * 3 + 1];
    int z = coords[id * 3 + 2];
    unsigned idx = ((unsigned)x << 12) | ((unsigned)y << 6) | (unsigned)z;
    atomicOr(&bm[b * BM_WORDS + (idx >> 5)], 1u << (idx & 31u));
}

__global__ void __launch_bounds__(256)
compute(const int* __restrict__ coords, const unsigned* __restrict__ bm,
        float* __restrict__ out) {
    const int pid = blockIdx.x;          // 0..8191 == b*2048 + n
    const int tid = threadIdx.x;
    const int b = pid >> 11;
    const unsigned* bmb = bm + b * BM_WORDS;

    // wave-uniform (blockIdx-derived) -> scalar loads
    const int x = coords[pid * 3 + 0];
    const int y = coords[pid * 3 + 1];
    const int z = coords[pid * 3 + 2];

    const bool nxm = bm_test(bmb, x - 1, y, z);
    const bool nxp = bm_test(bmb, x + 1, y, z);
    const bool nym = bm_test(bmb, x, y - 1, z);
    const bool nyp = bm_test(bmb, x, y + 1, z);
    const bool nzm = bm_test(bmb, x, y, z - 1);
    const bool nzp = bm_test(bmb, x, y, z + 1);

    const float inv15 = 1.0f / 15.0f;

    // z-face pattern is j-invariant per thread: v = 1024j + 4*tid,
    // iz0 = v & 15 = (4*tid) & 15.
    const int iz0 = (tid * 4) & 15;
    float zc[4];
    #pragma unroll
    for (int k = 0; k < 4; ++k) {
        float gz = (float)(iz0 + k) * inv15;
        zc[k] = fminf(nzm ? 1.0f : gz, nzp ? 1.0f : 1.0f - gz);
    }

    vfloat4* __restrict__ outp = (vfloat4*)(out + (size_t)pid * 4096);
    #pragma unroll
    for (int j = 0; j < 4; ++j) {
        int v = j * 1024 + tid * 4;
        float gx = (float)((v >> 8) & 15) * inv15;
        float gy = (float)((v >> 4) & 15) * inv15;
        float m = fminf(fminf(nxm ? 1.0f : gx, nxp ? 1.0f : 1.0f - gx),
                        fminf(nym ? 1.0f : gy, nyp ? 1.0f : 1.0f - gy));
        vfloat4 r;
        r.x = fminf(m, zc[0]);
        r.y = fminf(m, zc[1]);
        r.z = fminf(m, zc[2]);
        r.w = fminf(m, zc[3]);
        __builtin_nontemporal_store(r, &outp[j * 256 + tid]);
    }

    // occ [B,N,26]: per-lane divergent bitmap lookups (L2-hot, 32 KB/batch)
    if (tid < 26) {
        bool hit = bm_test(bmb, x + NB_OFF[tid][0], y + NB_OFF[tid][1],
                           z + NB_OFF[tid][2]);
        out[PRIOR_ELEMS + (size_t)pid * 26 + tid] = hit ? 1.0f : 0.0f;
    }
}

extern "C" void kernel_launch(void* const* d_in, const int* in_sizes, int n_in,
                              void* d_out, int out_size, void* d_ws, size_t ws_size,
                              hipStream_t stream) {
    const int* coords = (const int*)d_in[0];
    float* out = (float*)d_out;
    unsigned* bm = (unsigned*)d_ws;

    (void)hipMemsetAsync(bm, 0, (size_t)B * BM_WORDS * sizeof(unsigned), stream);
    scatter_bits<<<(B * N + 255) / 256, 256, 0, stream>>>(coords, bm);
    compute<<<B * N, 256, 0, stream>>>(coords, bm, out);
}